// Round 6
// baseline (429.657 us; speedup 1.0000x reference)
//
#include <hip/hip_runtime.h>
#include <math.h>

namespace {

constexpr int N = 50000;
constexpr int E = 400000;
constexpr int G = 64;
constexpr int HID = 64;
constexpr int HH = 256; // NHEAD*HID
constexpr int NCT = 32; // 512 output cols (xl|xr) / 16
constexpr float NEG = 0.2f;
constexpr int GAT_BLOCKS = 2048; // 8 blocks/CU * 256 CU
constexpr int GAT_WAVES = GAT_BLOCKS * 4;

typedef __attribute__((ext_vector_type(8))) short short8v;
typedef __attribute__((ext_vector_type(4))) float f32x4;

__device__ __forceinline__ unsigned short f2bf(float f) {
    unsigned int u = __float_as_uint(f);
    u += 0x7FFFu + ((u >> 16) & 1u); // RTNE
    return (unsigned short)(u >> 16);
}
__device__ __forceinline__ float bf2f(unsigned short h) {
    return __uint_as_float(((unsigned int)h) << 16);
}
// load 4 consecutive bf16 (8B aligned) -> float4
__device__ __forceinline__ float4 ld_bf4(const unsigned short* p) {
    uint2 u = *(const uint2*)p;
    float4 r;
    r.x = __uint_as_float(u.x << 16);
    r.y = __uint_as_float(u.x & 0xFFFF0000u);
    r.z = __uint_as_float(u.y << 16);
    r.w = __uint_as_float(u.y & 0xFFFF0000u);
    return r;
}

// ---- degree histogram + per-edge rank (deg pre-zeroed by memset) ----
__global__ __launch_bounds__(256) void hist_k(
    const int* __restrict__ dst, int* __restrict__ deg, int* __restrict__ rank)
{
    int e = blockIdx.x * 256 + threadIdx.x;
    if (e < E) rank[e] = atomicAdd(&deg[dst[e]], 1);
}

// block-local exclusive prefix of deg -> pre; per-block totals -> bsum
__global__ __launch_bounds__(256) void scan1_k(
    const int* __restrict__ deg, int* __restrict__ pre, int* __restrict__ bsum)
{
    __shared__ int s[256];
    int i = blockIdx.x * 256 + threadIdx.x;
    int v = (i < N) ? deg[i] : 0;
    s[threadIdx.x] = v;
    __syncthreads();
    for (int off = 1; off < 256; off <<= 1) {
        int t = (threadIdx.x >= off) ? s[threadIdx.x - off] : 0;
        __syncthreads();
        s[threadIdx.x] += t;
        __syncthreads();
    }
    if (i < N) pre[i] = s[threadIdx.x] - v;
    if (threadIdx.x == 255) bsum[blockIdx.x] = s[255];
}

// exclusive prefix over block totals (in place)
__global__ __launch_bounds__(256) void scan2_k(int* __restrict__ bsum, int nb)
{
    __shared__ int s[256];
    int tid = threadIdx.x;
    int v = (tid < nb) ? bsum[tid] : 0;
    s[tid] = v;
    __syncthreads();
    for (int off = 1; off < 256; off <<= 1) {
        int t = (tid >= off) ? s[tid - off] : 0;
        __syncthreads();
        s[tid] += t;
        __syncthreads();
    }
    if (tid < nb) bsum[tid] = s[tid] - v;
}

// ---- scatter edges to CSR order (no atomics); compute eap on the fly ----
__global__ __launch_bounds__(256) void scatter_k(
    const int* __restrict__ src, const int* __restrict__ dst,
    const float* __restrict__ ea,
    const float* __restrict__ W_et, const float* __restrict__ b_et,
    const float* __restrict__ W_uw, const float* __restrict__ b_uw,
    const float* __restrict__ W_ua, const float* __restrict__ b_ua,
    const int* __restrict__ pre, const int* __restrict__ bsum,
    const int* __restrict__ rank,
    int* __restrict__ csr_src, float* __restrict__ eap_csr)
{
    int e = blockIdx.x * 256 + threadIdx.x;
    if (e >= E) return;
    float et = ea[e * 2 + 0], uw = ea[e * 2 + 1];
    float ua = 1.f / (1.f + expf(-(uw * W_ua[0] + b_ua[0])));
    float4 v;
    v.x = et * W_et[0] + b_et[0];
    v.y = et * W_et[1] + b_et[1];
    v.z = (uw * W_uw[0] + b_uw[0]) * ua;
    v.w = (uw * W_uw[1] + b_uw[1]) * ua;
    int d = dst[e];
    int pos = pre[d] + bsum[d >> 8] + rank[e];
    csr_src[pos] = src[e];
    *(float4*)&eap_csr[(size_t)pos * 4] = v;
}

// ---- pack W (Wl|Wr as 512 cols) into MFMA B-fragment order, hi/lo bf16 ----
// slot: ((kt*NCT + ct)*64 + lane)*8 + e  holds  W[kt*32 + (lane>>4)*8 + e][ct*16 + (lane&15)]
// Runs AFTER scatter_k; outputs alias the then-dead `rank` buffer.
__global__ __launch_bounds__(256) void pack_k(
    const float* __restrict__ Wl0, const float* __restrict__ Wr0,
    const float* __restrict__ bl0, const float* __restrict__ br0,
    const float* __restrict__ Wl1, const float* __restrict__ Wr1,
    const float* __restrict__ bl1, const float* __restrict__ br1,
    unsigned short* __restrict__ w0hi, unsigned short* __restrict__ w0lo,
    unsigned short* __restrict__ w1hi, unsigned short* __restrict__ w1lo,
    float* __restrict__ bc0, float* __restrict__ bc1)
{
    int idx = blockIdx.x * 256 + threadIdx.x;
    if (idx < 8192) { // layer0: KT=4, 4*32*64 slots
        int lane = idx & 63, ct = (idx >> 6) & 31, kt = idx >> 11;
        int col = ct * 16 + (lane & 15);
        const float* W = (col < 256) ? Wl0 : Wr0;
        int c = col & 255;
        int kb = kt * 32 + ((lane >> 4) & 3) * 8;
#pragma unroll
        for (int e = 0; e < 8; e++) {
            float v = W[(size_t)(kb + e) * 256 + c];
            unsigned short hi = f2bf(v);
            unsigned short lo = f2bf(v - bf2f(hi));
            w0hi[(size_t)idx * 8 + e] = hi;
            w0lo[(size_t)idx * 8 + e] = lo;
        }
    } else if (idx < 8192 + 4096) { // layer1: KT=2
        int s = idx - 8192;
        int lane = s & 63, ct = (s >> 6) & 31, kt = s >> 11;
        int col = ct * 16 + (lane & 15);
        const float* W = (col < 256) ? Wl1 : Wr1;
        int c = col & 255;
        int kb = kt * 32 + ((lane >> 4) & 3) * 8;
#pragma unroll
        for (int e = 0; e < 8; e++) {
            float v = W[(size_t)(kb + e) * 256 + c];
            unsigned short hi = f2bf(v);
            unsigned short lo = f2bf(v - bf2f(hi));
            w1hi[(size_t)s * 8 + e] = hi;
            w1lo[(size_t)s * 8 + e] = lo;
        }
    } else if (idx < 8192 + 4096 + 512) {
        int i = idx - (8192 + 4096);
        bc0[i] = (i < 256) ? bl0[i] : br0[i - 256];
    } else if (idx < 8192 + 4096 + 1024) {
        int i = idx - (8192 + 4096 + 512);
        bc1[i] = (i < 256) ? bl1[i] : br1[i - 256];
    }
}

// ---- node projection via split-bf16 MFMA; outputs stored as bf16 ----
// block: 32 nodes x 512 cols. 4 waves; wave w: both 16-row tiles, col-tiles [8w, 8w+8).
template <int IC>
__global__ __launch_bounds__(256) void projmm_k(
    const float* __restrict__ x,
    const unsigned short* __restrict__ whi, const unsigned short* __restrict__ wlo,
    const float* __restrict__ bc,
    unsigned short* __restrict__ xlb, unsigned short* __restrict__ xrb)
{
    constexpr int KT = IC / 32;
    constexpr int LDX = IC + 4; // pad: row stride stays 16B-aligned, banks spread
    __shared__ float xs[32][LDX];
    const int base = blockIdx.x * 32;
    const int tid = threadIdx.x;
    for (int idx = tid; idx < 32 * IC / 4; idx += 256) {
        int j = idx / (IC / 4), k4 = idx - j * (IC / 4);
        int n = base + j;
        float4 v = make_float4(0.f, 0.f, 0.f, 0.f);
        if (n < N) v = *(const float4*)&x[(size_t)n * IC + k4 * 4];
        *(float4*)&xs[j][k4 * 4] = v;
    }
    __syncthreads();
    const int w = tid >> 6, lane = tid & 63;
    const int lr = lane & 15, lg = lane >> 4;
    f32x4 acc[2][8];
#pragma unroll
    for (int rt = 0; rt < 2; rt++)
#pragma unroll
        for (int ct = 0; ct < 8; ct++) {
            f32x4 z = {0.f, 0.f, 0.f, 0.f};
            acc[rt][ct] = z;
        }
#pragma unroll
    for (int kt = 0; kt < KT; kt++) {
        short8v ahi[2], alo[2];
#pragma unroll
        for (int rt = 0; rt < 2; rt++) {
            const float* p = &xs[rt * 16 + lr][kt * 32 + lg * 8];
            float4 v0 = *(const float4*)p;
            float4 v1 = *(const float4*)(p + 4);
            float fv[8] = {v0.x, v0.y, v0.z, v0.w, v1.x, v1.y, v1.z, v1.w};
            short8v h, l;
#pragma unroll
            for (int e = 0; e < 8; e++) {
                unsigned short hb = f2bf(fv[e]);
                h[e] = (short)hb;
                l[e] = (short)f2bf(fv[e] - bf2f(hb));
            }
            ahi[rt] = h;
            alo[rt] = l;
        }
        const size_t bbase = ((size_t)(kt * NCT + w * 8) * 64 + lane) * 8;
#pragma unroll
        for (int ct = 0; ct < 8; ct++) {
            short8v bhi = *(const short8v*)&whi[bbase + (size_t)ct * 64 * 8];
            short8v blo = *(const short8v*)&wlo[bbase + (size_t)ct * 64 * 8];
#pragma unroll
            for (int rt = 0; rt < 2; rt++) {
                acc[rt][ct] = __builtin_amdgcn_mfma_f32_16x16x32_bf16(ahi[rt], bhi, acc[rt][ct], 0, 0, 0);
                acc[rt][ct] = __builtin_amdgcn_mfma_f32_16x16x32_bf16(alo[rt], bhi, acc[rt][ct], 0, 0, 0);
                acc[rt][ct] = __builtin_amdgcn_mfma_f32_16x16x32_bf16(ahi[rt], blo, acc[rt][ct], 0, 0, 0);
            }
        }
    }
    // epilogue: C/D layout (measured): col = lane&15, row = (lane>>4)*4 + reg
#pragma unroll
    for (int ct = 0; ct < 8; ct++) {
        int col = (w * 8 + ct) * 16 + lr;
        float bv = bc[col];
        unsigned short* target;
        int c;
        if (col < 256) { target = xlb; c = col; }
        else           { target = xrb; c = col - 256; }
#pragma unroll
        for (int rt = 0; rt < 2; rt++) {
            int row0 = base + rt * 16 + lg * 4;
            f32x4 a = acc[rt][ct];
#pragma unroll
            for (int i = 0; i < 4; i++) {
                int r = row0 + i;
                if (r < N) target[(size_t)r * HH + c] = f2bf(a[i] + bv);
            }
        }
    }
}

// ---- per-edge helpers for the fused GAT layer ----
__device__ __forceinline__ void edge_group4(
    int idx,
    const int* __restrict__ csr_src, const float* __restrict__ eap_csr,
    const unsigned short* __restrict__ xlb, int c4,
    const float4& vr, const float4& w0, const float4& w1,
    const float4& w2, const float4& w3, const float4& av,
    float& denom, float& ax, float& ay, float& az, float& aw)
{
    int s0 = csr_src[idx], s1 = csr_src[idx + 1];
    int s2 = csr_src[idx + 2], s3 = csr_src[idx + 3];
    float4 a0 = *(const float4*)&eap_csr[(size_t)(idx + 0) * 4];
    float4 a1 = *(const float4*)&eap_csr[(size_t)(idx + 1) * 4];
    float4 a2 = *(const float4*)&eap_csr[(size_t)(idx + 2) * 4];
    float4 a3 = *(const float4*)&eap_csr[(size_t)(idx + 3) * 4];
    float4 vl0 = ld_bf4(&xlb[(size_t)s0 * HH + c4]);
    float4 vl1 = ld_bf4(&xlb[(size_t)s1 * HH + c4]);
    float4 vl2 = ld_bf4(&xlb[(size_t)s2 * HH + c4]);
    float4 vl3 = ld_bf4(&xlb[(size_t)s3 * HH + c4]);
    float p0, p1, p2, p3;
    {
        float q0 = vl0.x + vr.x + a0.x * w0.x + a0.y * w1.x + a0.z * w2.x + a0.w * w3.x;
        float q1 = vl0.y + vr.y + a0.x * w0.y + a0.y * w1.y + a0.z * w2.y + a0.w * w3.y;
        float q2 = vl0.z + vr.z + a0.x * w0.z + a0.y * w1.z + a0.z * w2.z + a0.w * w3.z;
        float q3 = vl0.w + vr.w + a0.x * w0.w + a0.y * w1.w + a0.z * w2.w + a0.w * w3.w;
        q0 = fmaxf(q0, NEG * q0); q1 = fmaxf(q1, NEG * q1);
        q2 = fmaxf(q2, NEG * q2); q3 = fmaxf(q3, NEG * q3);
        p0 = q0 * av.x + q1 * av.y + q2 * av.z + q3 * av.w;
    }
    {
        float q0 = vl1.x + vr.x + a1.x * w0.x + a1.y * w1.x + a1.z * w2.x + a1.w * w3.x;
        float q1 = vl1.y + vr.y + a1.x * w0.y + a1.y * w1.y + a1.z * w2.y + a1.w * w3.y;
        float q2 = vl1.z + vr.z + a1.x * w0.z + a1.y * w1.z + a1.z * w2.z + a1.w * w3.z;
        float q3 = vl1.w + vr.w + a1.x * w0.w + a1.y * w1.w + a1.z * w2.w + a1.w * w3.w;
        q0 = fmaxf(q0, NEG * q0); q1 = fmaxf(q1, NEG * q1);
        q2 = fmaxf(q2, NEG * q2); q3 = fmaxf(q3, NEG * q3);
        p1 = q0 * av.x + q1 * av.y + q2 * av.z + q3 * av.w;
    }
    {
        float q0 = vl2.x + vr.x + a2.x * w0.x + a2.y * w1.x + a2.z * w2.x + a2.w * w3.x;
        float q1 = vl2.y + vr.y + a2.x * w0.y + a2.y * w1.y + a2.z * w2.y + a2.w * w3.y;
        float q2 = vl2.z + vr.z + a2.x * w0.z + a2.y * w1.z + a2.z * w2.z + a2.w * w3.z;
        float q3 = vl2.w + vr.w + a2.x * w0.w + a2.y * w1.w + a2.z * w2.w + a2.w * w3.w;
        q0 = fmaxf(q0, NEG * q0); q1 = fmaxf(q1, NEG * q1);
        q2 = fmaxf(q2, NEG * q2); q3 = fmaxf(q3, NEG * q3);
        p2 = q0 * av.x + q1 * av.y + q2 * av.z + q3 * av.w;
    }
    {
        float q0 = vl3.x + vr.x + a3.x * w0.x + a3.y * w1.x + a3.z * w2.x + a3.w * w3.x;
        float q1 = vl3.y + vr.y + a3.x * w0.y + a3.y * w1.y + a3.z * w2.y + a3.w * w3.y;
        float q2 = vl3.z + vr.z + a3.x * w0.z + a3.y * w1.z + a3.z * w2.z + a3.w * w3.z;
        float q3 = vl3.w + vr.w + a3.x * w0.w + a3.y * w1.w + a3.z * w2.w + a3.w * w3.w;
        q0 = fmaxf(q0, NEG * q0); q1 = fmaxf(q1, NEG * q1);
        q2 = fmaxf(q2, NEG * q2); q3 = fmaxf(q3, NEG * q3);
        p3 = q0 * av.x + q1 * av.y + q2 * av.z + q3 * av.w;
    }
#pragma unroll
    for (int off = 1; off <= 8; off <<= 1) {
        p0 += __shfl_xor(p0, off, 64);
        p1 += __shfl_xor(p1, off, 64);
        p2 += __shfl_xor(p2, off, 64);
        p3 += __shfl_xor(p3, off, 64);
    }
    float e0 = __expf(p0);
    float e1 = __expf(p1);
    float e2 = __expf(p2);
    float e3 = __expf(p3);
    denom += e0 + e1 + e2 + e3;
    ax += e0 * vl0.x + e1 * vl1.x + e2 * vl2.x + e3 * vl3.x;
    ay += e0 * vl0.y + e1 * vl1.y + e2 * vl2.y + e3 * vl3.y;
    az += e0 * vl0.z + e1 * vl1.z + e2 * vl2.z + e3 * vl3.z;
    aw += e0 * vl0.w + e1 * vl1.w + e2 * vl2.w + e3 * vl3.w;
}

__device__ __forceinline__ void edge_one(
    int idx,
    const int* __restrict__ csr_src, const float* __restrict__ eap_csr,
    const unsigned short* __restrict__ xlb, int c4,
    const float4& vr, const float4& w0, const float4& w1,
    const float4& w2, const float4& w3, const float4& av,
    float& denom, float& ax, float& ay, float& az, float& aw)
{
    int s = csr_src[idx];
    float4 a = *(const float4*)&eap_csr[(size_t)idx * 4];
    float4 vl = ld_bf4(&xlb[(size_t)s * HH + c4]);
    float q0 = vl.x + vr.x + a.x * w0.x + a.y * w1.x + a.z * w2.x + a.w * w3.x;
    float q1 = vl.y + vr.y + a.x * w0.y + a.y * w1.y + a.z * w2.y + a.w * w3.y;
    float q2 = vl.z + vr.z + a.x * w0.z + a.y * w1.z + a.z * w2.z + a.w * w3.z;
    float q3 = vl.w + vr.w + a.x * w0.w + a.y * w1.w + a.z * w2.w + a.w * w3.w;
    q0 = fmaxf(q0, NEG * q0); q1 = fmaxf(q1, NEG * q1);
    q2 = fmaxf(q2, NEG * q2); q3 = fmaxf(q3, NEG * q3);
    float p = q0 * av.x + q1 * av.y + q2 * av.z + q3 * av.w;
#pragma unroll
    for (int off = 1; off <= 8; off <<= 1) p += __shfl_xor(p, off, 64);
    float e = __expf(p);
    denom += e;
    ax += e * vl.x;
    ay += e * vl.y;
    az += e * vl.z;
    aw += e * vl.w;
}

// ---- fused GAT layer: persistent waves, static partition, shift-free softmax,
//      TWO dst nodes per wave (2 independent chains -> latency hiding) ----
__global__ __launch_bounds__(256) void gat_aggr_k(
    const unsigned short* __restrict__ xlb, const unsigned short* __restrict__ xrb,
    const float* __restrict__ eap_csr, const float* __restrict__ We,
    const float* __restrict__ att,
    const int* __restrict__ pre, const int* __restrict__ bsum,
    const int* __restrict__ deg,
    const int* __restrict__ csr_src,
    const float* __restrict__ bias, float* __restrict__ hout)
{
    const int lane = threadIdx.x & 63;
    const int c4 = lane * 4;
    const float4 w0 = *(const float4*)&We[0 * HH + c4];
    const float4 w1 = *(const float4*)&We[1 * HH + c4];
    const float4 w2 = *(const float4*)&We[2 * HH + c4];
    const float4 w3 = *(const float4*)&We[3 * HH + c4];
    const float4 av = *(const float4*)&att[c4];
    float4 bb = make_float4(0.f, 0.f, 0.f, 0.f);
    if (lane < 16) bb = *(const float4*)&bias[c4];

    const int wid = __builtin_amdgcn_readfirstlane(blockIdx.x * 4 + (threadIdx.x >> 6));
    constexpr int q = N / GAT_WAVES;           // 6
    constexpr int r = N % GAT_WAVES;           // 836
    int d0 = wid * q + (wid < r ? wid : r);
    int dend = d0 + q + (wid < r ? 1 : 0);

    for (int d = d0; d < dend; d += 2) {
        const int dA = d;
        const int dB = d + 1;
        const bool hasB = (dB < dend);          // wave-uniform
        int ia = pre[dA] + bsum[dA >> 8];
        int eA = ia + deg[dA];
        int ib = 0, eB = 0;
        if (hasB) { ib = pre[dB] + bsum[dB >> 8]; eB = ib + deg[dB]; }
        const float4 vrA = ld_bf4(&xrb[(size_t)dA * HH + c4]);
        const float4 vrB = ld_bf4(&xrb[(size_t)(hasB ? dB : dA) * HH + c4]);
        float dnA = 0.f, axA = 0.f, ayA = 0.f, azA = 0.f, awA = 0.f;
        float dnB = 0.f, axB = 0.f, ayB = 0.f, azB = 0.f, awB = 0.f;
        // joint phase: both chains active -> loads of one overlap math of the other
        while (ia + 4 <= eA && ib + 4 <= eB) {
            edge_group4(ia, csr_src, eap_csr, xlb, c4, vrA, w0, w1, w2, w3, av,
                        dnA, axA, ayA, azA, awA);
            edge_group4(ib, csr_src, eap_csr, xlb, c4, vrB, w0, w1, w2, w3, av,
                        dnB, axB, ayB, azB, awB);
            ia += 4; ib += 4;
        }
        for (; ia + 4 <= eA; ia += 4)
            edge_group4(ia, csr_src, eap_csr, xlb, c4, vrA, w0, w1, w2, w3, av,
                        dnA, axA, ayA, azA, awA);
        for (; ib + 4 <= eB; ib += 4)
            edge_group4(ib, csr_src, eap_csr, xlb, c4, vrB, w0, w1, w2, w3, av,
                        dnB, axB, ayB, azB, awB);
        for (; ia < eA; ++ia)
            edge_one(ia, csr_src, eap_csr, xlb, c4, vrA, w0, w1, w2, w3, av,
                     dnA, axA, ayA, azA, awA);
        for (; ib < eB; ++ib)
            edge_one(ib, csr_src, eap_csr, xlb, c4, vrB, w0, w1, w2, w3, av,
                     dnB, axB, ayB, azB, awB);
        // finalize A
        {
            float inv = 0.25f / (dnA + 1e-16f);   // head-mean folded in
            axA *= inv; ayA *= inv; azA *= inv; awA *= inv;
            axA += __shfl_xor(axA, 16, 64); axA += __shfl_xor(axA, 32, 64);
            ayA += __shfl_xor(ayA, 16, 64); ayA += __shfl_xor(ayA, 32, 64);
            azA += __shfl_xor(azA, 16, 64); azA += __shfl_xor(azA, 32, 64);
            awA += __shfl_xor(awA, 16, 64); awA += __shfl_xor(awA, 32, 64);
            if (lane < 16) {
                float4 o;
                o.x = fmaxf(axA + bb.x, 0.f);
                o.y = fmaxf(ayA + bb.y, 0.f);
                o.z = fmaxf(azA + bb.z, 0.f);
                o.w = fmaxf(awA + bb.w, 0.f);
                *(float4*)&hout[(size_t)dA * HID + c4] = o;
            }
        }
        // finalize B
        if (hasB) {
            float inv = 0.25f / (dnB + 1e-16f);
            axB *= inv; ayB *= inv; azB *= inv; awB *= inv;
            axB += __shfl_xor(axB, 16, 64); axB += __shfl_xor(axB, 32, 64);
            ayB += __shfl_xor(ayB, 16, 64); ayB += __shfl_xor(ayB, 32, 64);
            azB += __shfl_xor(azB, 16, 64); azB += __shfl_xor(azB, 32, 64);
            awB += __shfl_xor(awB, 16, 64); awB += __shfl_xor(awB, 32, 64);
            if (lane < 16) {
                float4 o;
                o.x = fmaxf(axB + bb.x, 0.f);
                o.y = fmaxf(ayB + bb.y, 0.f);
                o.z = fmaxf(azB + bb.z, 0.f);
                o.w = fmaxf(awB + bb.w, 0.f);
                *(float4*)&hout[(size_t)dB * HID + c4] = o;
            }
        }
    }
}

// ---- pooling: chunked segment sum (batch is sorted) ----
__global__ __launch_bounds__(256) void pool_k(
    const float* __restrict__ h, const int* __restrict__ batch,
    float* __restrict__ pooled)
{
    constexpr int CH = 16;
    int c = threadIdx.x & 63;
    int chunk = blockIdx.x * 4 + (threadIdx.x >> 6);
    int n0 = chunk * CH;
    if (n0 >= N) return;
    int nend = (n0 + CH < N) ? n0 + CH : N;
    float sum = 0.f;
    int curb = batch[n0];
    for (int n = n0; n < nend; ++n) {
        int b = batch[n];
        if (b != curb) {
            atomicAdd(&pooled[curb * HID + c], sum);
            sum = 0.f; curb = b;
        }
        sum += h[(size_t)n * HID + c];
    }
    atomicAdd(&pooled[curb * HID + c], sum);
}

// ---- MLP head: one block (64 threads) per graph ----
__global__ __launch_bounds__(64) void head_k(
    const float* __restrict__ pooled, const int* __restrict__ batch,
    const float* __restrict__ W_fc, const float* __restrict__ b_fc,
    const float* __restrict__ W_res, const float* __restrict__ b_res,
    const float* __restrict__ W_time, const float* __restrict__ b_time,
    float* __restrict__ out)
{
    int g = blockIdx.x;
    int c = threadIdx.x;
    int lo = 0, hi = N;
    while (lo < hi) { int mid = (lo + hi) >> 1; if (batch[mid] < g) lo = mid + 1; else hi = mid; }
    int start = lo;
    hi = N;
    while (lo < hi) { int mid = (lo + hi) >> 1; if (batch[mid] < g + 1) lo = mid + 1; else hi = mid; }
    int end = lo;
    float cnt = (float)(end - start);
    float p = pooled[g * HID + c] / fmaxf(cnt, 1.0f);
    __shared__ float ps[HID];
    ps[c] = p;
    __syncthreads();
    float gv = b_fc[c];
    for (int k = 0; k < HID; k++) gv += ps[k] * W_fc[k * HID + c];
    gv = fmaxf(gv, 0.f);
    float r = gv * W_res[c];
    float t = gv * W_time[c];
#pragma unroll
    for (int off = 32; off > 0; off >>= 1) {
        r += __shfl_down(r, off, 64);
        t += __shfl_down(t, off, 64);
    }
    if (c == 0) {
        out[g * 2 + 0] = r + b_res[0];
        out[g * 2 + 1] = t + b_time[0];
    }
}

} // namespace

extern "C" void kernel_launch(void* const* d_in, const int* in_sizes, int n_in,
                              void* d_out, int out_size, void* d_ws, size_t ws_size,
                              hipStream_t stream) {
    const float* x         = (const float*)d_in[0];
    const float* edge_attr = (const float*)d_in[1];
    const int*   edge_index= (const int*)d_in[2];
    const int*   batch     = (const int*)d_in[3];
    const float* W_et = (const float*)d_in[4];
    const float* b_et = (const float*)d_in[5];
    const float* W_uw = (const float*)d_in[6];
    const float* b_uw = (const float*)d_in[7];
    const float* W_ua = (const float*)d_in[8];
    const float* b_ua = (const float*)d_in[9];
    const float* Wl0  = (const float*)d_in[10];
    const float* bl0  = (const float*)d_in[11];
    const float* Wr0  = (const float*)d_in[12];
    const float* br0  = (const float*)d_in[13];
    const float* att0 = (const float*)d_in[14];
    const float* We0  = (const float*)d_in[15];
    const float* bias0= (const float*)d_in[16];
    const float* Wl1  = (const float*)d_in[17];
    const float* bl1  = (const float*)d_in[18];
    const float* Wr1  = (const float*)d_in[19];
    const float* br1  = (const float*)d_in[20];
    const float* att1 = (const float*)d_in[21];
    const float* We1  = (const float*)d_in[22];
    const float* bias1= (const float*)d_in[23];
    const float* W_fc = (const float*)d_in[24];
    const float* b_fc = (const float*)d_in[25];
    const float* W_res= (const float*)d_in[26];
    const float* b_res= (const float*)d_in[27];
    const float* W_time=(const float*)d_in[28];
    const float* b_time=(const float*)d_in[29];

    const int* src = edge_index;     // row 0
    const int* dst = edge_index + E; // row 1

    // workspace layout — IDENTICAL footprint to the known-good 465us kernel.
    // xl/xr regions are sized for fp32 but now hold bf16 (half used; stride kept).
    float* ws    = (float*)d_ws;
    unsigned short* xlb = (unsigned short*)ws;               // in N*HH float region
    unsigned short* xrb = (unsigned short*)(ws + (size_t)N * HH); // in N*HH float region
    float* h1    = ws  + (size_t)2 * N * HH;  // N*HID
    float* h2    = h1  + (size_t)N * HID;     // N*HID
    float* pooled= h2  + (size_t)N * HID;     // G*HID
    int*   deg      = (int*)(pooled + (size_t)G * HID); // N (adjacent to pooled)
    int*   pre      = deg + N;                // N
    int*   bsum     = pre + N;                // 256
    int*   rank     = bsum + 256;             // E (dead after scatter_k)
    int*   csr_src  = rank + E;               // E
    float* eap_csr  = (float*)(csr_src + E);  // E*4
    // packed MFMA weight fragments + biases ALIAS the dead `rank` buffer
    // (needs ~397 KB of rank's 1.6 MB; written by pack_k AFTER scatter_k)
    unsigned short* w0hi = (unsigned short*)rank;   // 65536 ushorts
    unsigned short* w0lo = w0hi + 65536;            // 65536
    unsigned short* w1hi = w0lo + 65536;            // 32768
    unsigned short* w1lo = w1hi + 32768;            // 32768
    float* bc0 = (float*)(w1lo + 32768);            // 512 floats
    float* bc1 = bc0 + 512;                         // 512 floats

    dim3 b256(256);
    const int NB = (N + 255) / 256; // 196
    const int NPROJ = (N + 31) / 32; // 1563

    // zero pooled + deg in one memset (adjacent in layout)
    hipMemsetAsync(pooled, 0, (size_t)(G * HID + N) * 4, stream);
    // CSR build (rank-based, no scatter atomics)
    hist_k<<<(E + 255) / 256, b256, 0, stream>>>(dst, deg, rank);
    scan1_k<<<NB, b256, 0, stream>>>(deg, pre, bsum);
    scan2_k<<<1, b256, 0, stream>>>(bsum, NB);
    scatter_k<<<(E + 255) / 256, b256, 0, stream>>>(
        src, dst, edge_attr, W_et, b_et, W_uw, b_uw, W_ua, b_ua,
        pre, bsum, rank, csr_src, eap_csr);
    // weight packing AFTER scatter (rank is dead now; pack output aliases it)
    pack_k<<<52, b256, 0, stream>>>(Wl0, Wr0, bl0, br0, Wl1, Wr1, bl1, br1,
                                    w0hi, w0lo, w1hi, w1lo, bc0, bc1);

    // ---------- layer 0 ----------
    projmm_k<128><<<NPROJ, b256, 0, stream>>>(x, w0hi, w0lo, bc0, xlb, xrb);
    gat_aggr_k<<<GAT_BLOCKS, b256, 0, stream>>>(
        xlb, xrb, eap_csr, We0, att0, pre, bsum, deg, csr_src, bias0, h1);

    // ---------- layer 1 ----------
    projmm_k<64><<<NPROJ, b256, 0, stream>>>(h1, w1hi, w1lo, bc1, xlb, xrb);
    gat_aggr_k<<<GAT_BLOCKS, b256, 0, stream>>>(
        xlb, xrb, eap_csr, We1, att1, pre, bsum, deg, csr_src, bias1, h2);

    // ---------- pooling + head ----------
    pool_k<<<((N + 15) / 16 + 3) / 4, b256, 0, stream>>>(h2, batch, pooled);
    head_k<<<G, dim3(64), 0, stream>>>(
        pooled, batch, W_fc, b_fc, W_res, b_res, W_time, b_time, (float*)d_out);
}

// Round 7
// 366.512 us; speedup vs baseline: 1.1723x; 1.1723x over previous
//
#include <hip/hip_runtime.h>
#include <math.h>

namespace {

constexpr int N = 50000;
constexpr int E = 400000;
constexpr int G = 64;
constexpr int HID = 64;
constexpr int HH = 256; // NHEAD*HID
constexpr int NCT = 32; // 512 output cols (xl|xr) / 16
constexpr float NEG = 0.2f;
constexpr int GAT_BLOCKS = 2048; // 8 blocks/CU * 256 CU
constexpr int GAT_WAVES = GAT_BLOCKS * 4;

typedef __attribute__((ext_vector_type(8))) short short8v;
typedef __attribute__((ext_vector_type(4))) float f32x4;

__device__ __forceinline__ unsigned short f2bf(float f) {
    unsigned int u = __float_as_uint(f);
    u += 0x7FFFu + ((u >> 16) & 1u); // RTNE
    return (unsigned short)(u >> 16);
}
__device__ __forceinline__ float bf2f(unsigned short h) {
    return __uint_as_float(((unsigned int)h) << 16);
}
// load 4 consecutive bf16 (8B aligned) -> float4
__device__ __forceinline__ float4 ld_bf4(const unsigned short* p) {
    uint2 u = *(const uint2*)p;
    float4 r;
    r.x = __uint_as_float(u.x << 16);
    r.y = __uint_as_float(u.x & 0xFFFF0000u);
    r.z = __uint_as_float(u.y << 16);
    r.w = __uint_as_float(u.y & 0xFFFF0000u);
    return r;
}

// ---- degree histogram + per-edge rank (deg pre-zeroed by memset) ----
__global__ __launch_bounds__(256) void hist_k(
    const int* __restrict__ dst, int* __restrict__ deg, int* __restrict__ rank)
{
    int e = blockIdx.x * 256 + threadIdx.x;
    if (e < E) rank[e] = atomicAdd(&deg[dst[e]], 1);
}

// block-local exclusive prefix of deg -> pre; per-block totals -> bsum
__global__ __launch_bounds__(256) void scan1_k(
    const int* __restrict__ deg, int* __restrict__ pre, int* __restrict__ bsum)
{
    __shared__ int s[256];
    int i = blockIdx.x * 256 + threadIdx.x;
    int v = (i < N) ? deg[i] : 0;
    s[threadIdx.x] = v;
    __syncthreads();
    for (int off = 1; off < 256; off <<= 1) {
        int t = (threadIdx.x >= off) ? s[threadIdx.x - off] : 0;
        __syncthreads();
        s[threadIdx.x] += t;
        __syncthreads();
    }
    if (i < N) pre[i] = s[threadIdx.x] - v;
    if (threadIdx.x == 255) bsum[blockIdx.x] = s[255];
}

// exclusive prefix over block totals (in place)
__global__ __launch_bounds__(256) void scan2_k(int* __restrict__ bsum, int nb)
{
    __shared__ int s[256];
    int tid = threadIdx.x;
    int v = (tid < nb) ? bsum[tid] : 0;
    s[tid] = v;
    __syncthreads();
    for (int off = 1; off < 256; off <<= 1) {
        int t = (tid >= off) ? s[tid - off] : 0;
        __syncthreads();
        s[tid] += t;
        __syncthreads();
    }
    if (tid < nb) bsum[tid] = s[tid] - v;
}

// ---- scatter edges to CSR order (no atomics); compute eap on the fly ----
__global__ __launch_bounds__(256) void scatter_k(
    const int* __restrict__ src, const int* __restrict__ dst,
    const float* __restrict__ ea,
    const float* __restrict__ W_et, const float* __restrict__ b_et,
    const float* __restrict__ W_uw, const float* __restrict__ b_uw,
    const float* __restrict__ W_ua, const float* __restrict__ b_ua,
    const int* __restrict__ pre, const int* __restrict__ bsum,
    const int* __restrict__ rank,
    int* __restrict__ csr_src, float* __restrict__ eap_csr)
{
    int e = blockIdx.x * 256 + threadIdx.x;
    if (e >= E) return;
    float et = ea[e * 2 + 0], uw = ea[e * 2 + 1];
    float ua = 1.f / (1.f + expf(-(uw * W_ua[0] + b_ua[0])));
    float4 v;
    v.x = et * W_et[0] + b_et[0];
    v.y = et * W_et[1] + b_et[1];
    v.z = (uw * W_uw[0] + b_uw[0]) * ua;
    v.w = (uw * W_uw[1] + b_uw[1]) * ua;
    int d = dst[e];
    int pos = pre[d] + bsum[d >> 8] + rank[e];
    csr_src[pos] = src[e];
    *(float4*)&eap_csr[(size_t)pos * 4] = v;
}

// ---- pack W (Wl|Wr as 512 cols) into MFMA B-fragment order, hi/lo bf16 ----
// slot: ((kt*NCT + ct)*64 + lane)*8 + e  holds  W[kt*32 + (lane>>4)*8 + e][ct*16 + (lane&15)]
// Runs AFTER scatter_k; outputs alias the then-dead `rank` buffer.
__global__ __launch_bounds__(256) void pack_k(
    const float* __restrict__ Wl0, const float* __restrict__ Wr0,
    const float* __restrict__ bl0, const float* __restrict__ br0,
    const float* __restrict__ Wl1, const float* __restrict__ Wr1,
    const float* __restrict__ bl1, const float* __restrict__ br1,
    unsigned short* __restrict__ w0hi, unsigned short* __restrict__ w0lo,
    unsigned short* __restrict__ w1hi, unsigned short* __restrict__ w1lo,
    float* __restrict__ bc0, float* __restrict__ bc1)
{
    int idx = blockIdx.x * 256 + threadIdx.x;
    if (idx < 8192) { // layer0: KT=4, 4*32*64 slots
        int lane = idx & 63, ct = (idx >> 6) & 31, kt = idx >> 11;
        int col = ct * 16 + (lane & 15);
        const float* W = (col < 256) ? Wl0 : Wr0;
        int c = col & 255;
        int kb = kt * 32 + ((lane >> 4) & 3) * 8;
#pragma unroll
        for (int e = 0; e < 8; e++) {
            float v = W[(size_t)(kb + e) * 256 + c];
            unsigned short hi = f2bf(v);
            unsigned short lo = f2bf(v - bf2f(hi));
            w0hi[(size_t)idx * 8 + e] = hi;
            w0lo[(size_t)idx * 8 + e] = lo;
        }
    } else if (idx < 8192 + 4096) { // layer1: KT=2
        int s = idx - 8192;
        int lane = s & 63, ct = (s >> 6) & 31, kt = s >> 11;
        int col = ct * 16 + (lane & 15);
        const float* W = (col < 256) ? Wl1 : Wr1;
        int c = col & 255;
        int kb = kt * 32 + ((lane >> 4) & 3) * 8;
#pragma unroll
        for (int e = 0; e < 8; e++) {
            float v = W[(size_t)(kb + e) * 256 + c];
            unsigned short hi = f2bf(v);
            unsigned short lo = f2bf(v - bf2f(hi));
            w1hi[(size_t)s * 8 + e] = hi;
            w1lo[(size_t)s * 8 + e] = lo;
        }
    } else if (idx < 8192 + 4096 + 512) {
        int i = idx - (8192 + 4096);
        bc0[i] = (i < 256) ? bl0[i] : br0[i - 256];
    } else if (idx < 8192 + 4096 + 1024) {
        int i = idx - (8192 + 4096 + 512);
        bc1[i] = (i < 256) ? bl1[i] : br1[i - 256];
    }
}

// ---- node projection via split-bf16 MFMA; outputs stored as bf16 ----
// block: 32 nodes x 512 cols. 4 waves; wave w: both 16-row tiles, col-tiles [8w, 8w+8).
// Epilogue: stage bf16 tile in LDS (2 passes of 16 rows), store coalesced uint4.
template <int IC>
__global__ __launch_bounds__(256) void projmm_k(
    const float* __restrict__ x,
    const unsigned short* __restrict__ whi, const unsigned short* __restrict__ wlo,
    const float* __restrict__ bc,
    unsigned short* __restrict__ xlb, unsigned short* __restrict__ xrb)
{
    constexpr int KT = IC / 32;
    constexpr int LDX = IC + 4;     // pad: row stride stays 16B-aligned, banks spread
    constexpr int SROW = 516;       // bf16 stage row stride (1032B: write lands 2/bank)
    constexpr int XS_BYTES = 32 * LDX * 4;
    constexpr int ST_BYTES = 16 * SROW * 2;
    constexpr int SMEM_BYTES = (XS_BYTES > ST_BYTES) ? XS_BYTES : ST_BYTES;
    __shared__ char smem[SMEM_BYTES];
    float (*xs)[LDX] = (float (*)[LDX])smem;
    const int base = blockIdx.x * 32;
    const int tid = threadIdx.x;
    for (int idx = tid; idx < 32 * IC / 4; idx += 256) {
        int j = idx / (IC / 4), k4 = idx - j * (IC / 4);
        int n = base + j;
        float4 v = make_float4(0.f, 0.f, 0.f, 0.f);
        if (n < N) v = *(const float4*)&x[(size_t)n * IC + k4 * 4];
        *(float4*)&xs[j][k4 * 4] = v;
    }
    __syncthreads();
    const int w = tid >> 6, lane = tid & 63;
    const int lr = lane & 15, lg = lane >> 4;
    f32x4 acc[2][8];
#pragma unroll
    for (int rt = 0; rt < 2; rt++)
#pragma unroll
        for (int ct = 0; ct < 8; ct++) {
            f32x4 z = {0.f, 0.f, 0.f, 0.f};
            acc[rt][ct] = z;
        }
#pragma unroll
    for (int kt = 0; kt < KT; kt++) {
        short8v ahi[2], alo[2];
#pragma unroll
        for (int rt = 0; rt < 2; rt++) {
            const float* p = &xs[rt * 16 + lr][kt * 32 + lg * 8];
            float4 v0 = *(const float4*)p;
            float4 v1 = *(const float4*)(p + 4);
            float fv[8] = {v0.x, v0.y, v0.z, v0.w, v1.x, v1.y, v1.z, v1.w};
            short8v h, l;
#pragma unroll
            for (int e = 0; e < 8; e++) {
                unsigned short hb = f2bf(fv[e]);
                h[e] = (short)hb;
                l[e] = (short)f2bf(fv[e] - bf2f(hb));
            }
            ahi[rt] = h;
            alo[rt] = l;
        }
        const size_t bbase = ((size_t)(kt * NCT + w * 8) * 64 + lane) * 8;
#pragma unroll
        for (int ct = 0; ct < 8; ct++) {
            short8v bhi = *(const short8v*)&whi[bbase + (size_t)ct * 64 * 8];
            short8v blo = *(const short8v*)&wlo[bbase + (size_t)ct * 64 * 8];
#pragma unroll
            for (int rt = 0; rt < 2; rt++) {
                acc[rt][ct] = __builtin_amdgcn_mfma_f32_16x16x32_bf16(ahi[rt], bhi, acc[rt][ct], 0, 0, 0);
                acc[rt][ct] = __builtin_amdgcn_mfma_f32_16x16x32_bf16(alo[rt], bhi, acc[rt][ct], 0, 0, 0);
                acc[rt][ct] = __builtin_amdgcn_mfma_f32_16x16x32_bf16(ahi[rt], blo, acc[rt][ct], 0, 0, 0);
            }
        }
    }
    // epilogue: C/D layout (measured): col = lane&15, row = (lane>>4)*4 + reg
    __syncthreads(); // xs consumed into acc; reuse smem as bf16 stage
    unsigned short* st = (unsigned short*)smem;
#pragma unroll
    for (int rt = 0; rt < 2; rt++) {
        // write this 16-row half-tile into LDS (rows local 0..15)
#pragma unroll
        for (int ct = 0; ct < 8; ct++) {
            int col = (w * 8 + ct) * 16 + lr;
            float bv = bc[col];
            f32x4 a = acc[rt][ct];
#pragma unroll
            for (int i = 0; i < 4; i++) {
                st[(lg * 4 + i) * SROW + col] = f2bf(a[i] + bv);
            }
        }
        __syncthreads();
        // read back + coalesced 16B stores: 16 rows * 64 chunks(8 bf16) = 1024 chunks
        int rbase = base + rt * 16;
#pragma unroll
        for (int k = 0; k < 4; k++) {
            int ci = tid + k * 256;         // 0..1023
            int rl = ci >> 6;               // local row 0..15
            int cc = (ci & 63) * 8;         // col start (multiple of 8)
            int rg = rbase + rl;
            if (rg < N) {
                uint2 lo = *(const uint2*)&st[rl * SROW + cc];
                uint2 hi = *(const uint2*)&st[rl * SROW + cc + 4];
                uint4 val = make_uint4(lo.x, lo.y, hi.x, hi.y);
                if (cc < 256) *(uint4*)&xlb[(size_t)rg * HH + cc] = val;
                else          *(uint4*)&xrb[(size_t)rg * HH + (cc - 256)] = val;
            }
        }
        __syncthreads();
    }
}

// ---- fused GAT layer: persistent waves, static partition, shift-free softmax ----
// one 64-lane wave per dst node; lane l covers cols 4l..4l+3 (head = l>>4)
// (exact round-5 structure: best measured 71.4us/layer, VGPR 56)
__global__ __launch_bounds__(256) void gat_aggr_k(
    const unsigned short* __restrict__ xlb, const unsigned short* __restrict__ xrb,
    const float* __restrict__ eap_csr, const float* __restrict__ We,
    const float* __restrict__ att,
    const int* __restrict__ pre, const int* __restrict__ bsum,
    const int* __restrict__ deg,
    const int* __restrict__ csr_src,
    const float* __restrict__ bias, float* __restrict__ hout)
{
    const int lane = threadIdx.x & 63;
    const int c4 = lane * 4;
    const float4 w0 = *(const float4*)&We[0 * HH + c4];
    const float4 w1 = *(const float4*)&We[1 * HH + c4];
    const float4 w2 = *(const float4*)&We[2 * HH + c4];
    const float4 w3 = *(const float4*)&We[3 * HH + c4];
    const float4 av = *(const float4*)&att[c4];
    float4 bb = make_float4(0.f, 0.f, 0.f, 0.f);
    if (lane < 16) bb = *(const float4*)&bias[c4];

    const int wid = __builtin_amdgcn_readfirstlane(blockIdx.x * 4 + (threadIdx.x >> 6));
    constexpr int q = N / GAT_WAVES;           // 6
    constexpr int r = N % GAT_WAVES;           // 836
    int d0 = wid * q + (wid < r ? wid : r);
    int dcnt = q + (wid < r ? 1 : 0);

    for (int d = d0; d < d0 + dcnt; ++d) {
        int start = pre[d] + bsum[d >> 8];
        int end = start + deg[d];
        const float4 vr = ld_bf4(&xrb[(size_t)d * HH + c4]);
        float denom = 0.f;
        float ax = 0.f, ay = 0.f, az = 0.f, aw = 0.f;
        int idx = start;
        for (; idx + 4 <= end; idx += 4) {
            int s0 = csr_src[idx], s1 = csr_src[idx + 1];
            int s2 = csr_src[idx + 2], s3 = csr_src[idx + 3];
            float4 a0 = *(const float4*)&eap_csr[(size_t)(idx + 0) * 4];
            float4 a1 = *(const float4*)&eap_csr[(size_t)(idx + 1) * 4];
            float4 a2 = *(const float4*)&eap_csr[(size_t)(idx + 2) * 4];
            float4 a3 = *(const float4*)&eap_csr[(size_t)(idx + 3) * 4];
            float4 vl0 = ld_bf4(&xlb[(size_t)s0 * HH + c4]);
            float4 vl1 = ld_bf4(&xlb[(size_t)s1 * HH + c4]);
            float4 vl2 = ld_bf4(&xlb[(size_t)s2 * HH + c4]);
            float4 vl3 = ld_bf4(&xlb[(size_t)s3 * HH + c4]);
            float p0, p1, p2, p3;
            {
                float q0 = vl0.x + vr.x + a0.x * w0.x + a0.y * w1.x + a0.z * w2.x + a0.w * w3.x;
                float q1 = vl0.y + vr.y + a0.x * w0.y + a0.y * w1.y + a0.z * w2.y + a0.w * w3.y;
                float q2 = vl0.z + vr.z + a0.x * w0.z + a0.y * w1.z + a0.z * w2.z + a0.w * w3.z;
                float q3 = vl0.w + vr.w + a0.x * w0.w + a0.y * w1.w + a0.z * w2.w + a0.w * w3.w;
                q0 = fmaxf(q0, NEG * q0); q1 = fmaxf(q1, NEG * q1);
                q2 = fmaxf(q2, NEG * q2); q3 = fmaxf(q3, NEG * q3);
                p0 = q0 * av.x + q1 * av.y + q2 * av.z + q3 * av.w;
            }
            {
                float q0 = vl1.x + vr.x + a1.x * w0.x + a1.y * w1.x + a1.z * w2.x + a1.w * w3.x;
                float q1 = vl1.y + vr.y + a1.x * w0.y + a1.y * w1.y + a1.z * w2.y + a1.w * w3.y;
                float q2 = vl1.z + vr.z + a1.x * w0.z + a1.y * w1.z + a1.z * w2.z + a1.w * w3.z;
                float q3 = vl1.w + vr.w + a1.x * w0.w + a1.y * w1.w + a1.z * w2.w + a1.w * w3.w;
                q0 = fmaxf(q0, NEG * q0); q1 = fmaxf(q1, NEG * q1);
                q2 = fmaxf(q2, NEG * q2); q3 = fmaxf(q3, NEG * q3);
                p1 = q0 * av.x + q1 * av.y + q2 * av.z + q3 * av.w;
            }
            {
                float q0 = vl2.x + vr.x + a2.x * w0.x + a2.y * w1.x + a2.z * w2.x + a2.w * w3.x;
                float q1 = vl2.y + vr.y + a2.x * w0.y + a2.y * w1.y + a2.z * w2.y + a2.w * w3.y;
                float q2 = vl2.z + vr.z + a2.x * w0.z + a2.y * w1.z + a2.z * w2.z + a2.w * w3.z;
                float q3 = vl2.w + vr.w + a2.x * w0.w + a2.y * w1.w + a2.z * w2.w + a2.w * w3.w;
                q0 = fmaxf(q0, NEG * q0); q1 = fmaxf(q1, NEG * q1);
                q2 = fmaxf(q2, NEG * q2); q3 = fmaxf(q3, NEG * q3);
                p2 = q0 * av.x + q1 * av.y + q2 * av.z + q3 * av.w;
            }
            {
                float q0 = vl3.x + vr.x + a3.x * w0.x + a3.y * w1.x + a3.z * w2.x + a3.w * w3.x;
                float q1 = vl3.y + vr.y + a3.x * w0.y + a3.y * w1.y + a3.z * w2.y + a3.w * w3.y;
                float q2 = vl3.z + vr.z + a3.x * w0.z + a3.y * w1.z + a3.z * w2.z + a3.w * w3.z;
                float q3 = vl3.w + vr.w + a3.x * w0.w + a3.y * w1.w + a3.z * w2.w + a3.w * w3.w;
                q0 = fmaxf(q0, NEG * q0); q1 = fmaxf(q1, NEG * q1);
                q2 = fmaxf(q2, NEG * q2); q3 = fmaxf(q3, NEG * q3);
                p3 = q0 * av.x + q1 * av.y + q2 * av.z + q3 * av.w;
            }
#pragma unroll
            for (int off = 1; off <= 8; off <<= 1) {
                p0 += __shfl_xor(p0, off, 64);
                p1 += __shfl_xor(p1, off, 64);
                p2 += __shfl_xor(p2, off, 64);
                p3 += __shfl_xor(p3, off, 64);
            }
            float e0 = __expf(p0);
            float e1 = __expf(p1);
            float e2 = __expf(p2);
            float e3 = __expf(p3);
            denom += e0 + e1 + e2 + e3;
            ax += e0 * vl0.x + e1 * vl1.x + e2 * vl2.x + e3 * vl3.x;
            ay += e0 * vl0.y + e1 * vl1.y + e2 * vl2.y + e3 * vl3.y;
            az += e0 * vl0.z + e1 * vl1.z + e2 * vl2.z + e3 * vl3.z;
            aw += e0 * vl0.w + e1 * vl1.w + e2 * vl2.w + e3 * vl3.w;
        }
        for (; idx < end; ++idx) {
            int s = csr_src[idx];
            float4 a = *(const float4*)&eap_csr[(size_t)idx * 4];
            float4 vl = ld_bf4(&xlb[(size_t)s * HH + c4]);
            float q0 = vl.x + vr.x + a.x * w0.x + a.y * w1.x + a.z * w2.x + a.w * w3.x;
            float q1 = vl.y + vr.y + a.x * w0.y + a.y * w1.y + a.z * w2.y + a.w * w3.y;
            float q2 = vl.z + vr.z + a.x * w0.z + a.y * w1.z + a.z * w2.z + a.w * w3.z;
            float q3 = vl.w + vr.w + a.x * w0.w + a.y * w1.w + a.z * w2.w + a.w * w3.w;
            q0 = fmaxf(q0, NEG * q0); q1 = fmaxf(q1, NEG * q1);
            q2 = fmaxf(q2, NEG * q2); q3 = fmaxf(q3, NEG * q3);
            float p = q0 * av.x + q1 * av.y + q2 * av.z + q3 * av.w;
#pragma unroll
            for (int off = 1; off <= 8; off <<= 1) p += __shfl_xor(p, off, 64);
            float e = __expf(p);
            denom += e;
            ax += e * vl.x;
            ay += e * vl.y;
            az += e * vl.z;
            aw += e * vl.w;
        }
        float inv = 0.25f / (denom + 1e-16f);   // head-mean folded in
        ax *= inv; ay *= inv; az *= inv; aw *= inv;
        ax += __shfl_xor(ax, 16, 64); ax += __shfl_xor(ax, 32, 64);
        ay += __shfl_xor(ay, 16, 64); ay += __shfl_xor(ay, 32, 64);
        az += __shfl_xor(az, 16, 64); az += __shfl_xor(az, 32, 64);
        aw += __shfl_xor(aw, 16, 64); aw += __shfl_xor(aw, 32, 64);
        if (lane < 16) {
            float4 o;
            o.x = fmaxf(ax + bb.x, 0.f);
            o.y = fmaxf(ay + bb.y, 0.f);
            o.z = fmaxf(az + bb.z, 0.f);
            o.w = fmaxf(aw + bb.w, 0.f);
            *(float4*)&hout[(size_t)d * HID + c4] = o;
        }
    }
}

// ---- pooling: chunked segment sum (batch is sorted) ----
__global__ __launch_bounds__(256) void pool_k(
    const float* __restrict__ h, const int* __restrict__ batch,
    float* __restrict__ pooled)
{
    constexpr int CH = 16;
    int c = threadIdx.x & 63;
    int chunk = blockIdx.x * 4 + (threadIdx.x >> 6);
    int n0 = chunk * CH;
    if (n0 >= N) return;
    int nend = (n0 + CH < N) ? n0 + CH : N;
    float sum = 0.f;
    int curb = batch[n0];
    for (int n = n0; n < nend; ++n) {
        int b = batch[n];
        if (b != curb) {
            atomicAdd(&pooled[curb * HID + c], sum);
            sum = 0.f; curb = b;
        }
        sum += h[(size_t)n * HID + c];
    }
    atomicAdd(&pooled[curb * HID + c], sum);
}

// ---- MLP head: one block (64 threads) per graph ----
__global__ __launch_bounds__(64) void head_k(
    const float* __restrict__ pooled, const int* __restrict__ batch,
    const float* __restrict__ W_fc, const float* __restrict__ b_fc,
    const float* __restrict__ W_res, const float* __restrict__ b_res,
    const float* __restrict__ W_time, const float* __restrict__ b_time,
    float* __restrict__ out)
{
    int g = blockIdx.x;
    int c = threadIdx.x;
    int lo = 0, hi = N;
    while (lo < hi) { int mid = (lo + hi) >> 1; if (batch[mid] < g) lo = mid + 1; else hi = mid; }
    int start = lo;
    hi = N;
    while (lo < hi) { int mid = (lo + hi) >> 1; if (batch[mid] < g + 1) lo = mid + 1; else hi = mid; }
    int end = lo;
    float cnt = (float)(end - start);
    float p = pooled[g * HID + c] / fmaxf(cnt, 1.0f);
    __shared__ float ps[HID];
    ps[c] = p;
    __syncthreads();
    float gv = b_fc[c];
    for (int k = 0; k < HID; k++) gv += ps[k] * W_fc[k * HID + c];
    gv = fmaxf(gv, 0.f);
    float r = gv * W_res[c];
    float t = gv * W_time[c];
#pragma unroll
    for (int off = 32; off > 0; off >>= 1) {
        r += __shfl_down(r, off, 64);
        t += __shfl_down(t, off, 64);
    }
    if (c == 0) {
        out[g * 2 + 0] = r + b_res[0];
        out[g * 2 + 1] = t + b_time[0];
    }
}

} // namespace

extern "C" void kernel_launch(void* const* d_in, const int* in_sizes, int n_in,
                              void* d_out, int out_size, void* d_ws, size_t ws_size,
                              hipStream_t stream) {
    const float* x         = (const float*)d_in[0];
    const float* edge_attr = (const float*)d_in[1];
    const int*   edge_index= (const int*)d_in[2];
    const int*   batch     = (const int*)d_in[3];
    const float* W_et = (const float*)d_in[4];
    const float* b_et = (const float*)d_in[5];
    const float* W_uw = (const float*)d_in[6];
    const float* b_uw = (const float*)d_in[7];
    const float* W_ua = (const float*)d_in[8];
    const float* b_ua = (const float*)d_in[9];
    const float* Wl0  = (const float*)d_in[10];
    const float* bl0  = (const float*)d_in[11];
    const float* Wr0  = (const float*)d_in[12];
    const float* br0  = (const float*)d_in[13];
    const float* att0 = (const float*)d_in[14];
    const float* We0  = (const float*)d_in[15];
    const float* bias0= (const float*)d_in[16];
    const float* Wl1  = (const float*)d_in[17];
    const float* bl1  = (const float*)d_in[18];
    const float* Wr1  = (const float*)d_in[19];
    const float* br1  = (const float*)d_in[20];
    const float* att1 = (const float*)d_in[21];
    const float* We1  = (const float*)d_in[22];
    const float* bias1= (const float*)d_in[23];
    const float* W_fc = (const float*)d_in[24];
    const float* b_fc = (const float*)d_in[25];
    const float* W_res= (const float*)d_in[26];
    const float* b_res= (const float*)d_in[27];
    const float* W_time=(const float*)d_in[28];
    const float* b_time=(const float*)d_in[29];

    const int* src = edge_index;     // row 0
    const int* dst = edge_index + E; // row 1

    // workspace layout — IDENTICAL footprint to the known-good 465us kernel.
    // xl/xr regions are sized for fp32 but now hold bf16 (half used; stride kept).
    float* ws    = (float*)d_ws;
    unsigned short* xlb = (unsigned short*)ws;               // in N*HH float region
    unsigned short* xrb = (unsigned short*)(ws + (size_t)N * HH); // in N*HH float region
    float* h1    = ws  + (size_t)2 * N * HH;  // N*HID
    float* h2    = h1  + (size_t)N * HID;     // N*HID
    float* pooled= h2  + (size_t)N * HID;     // G*HID
    int*   deg      = (int*)(pooled + (size_t)G * HID); // N (adjacent to pooled)
    int*   pre      = deg + N;                // N
    int*   bsum     = pre + N;                // 256
    int*   rank     = bsum + 256;             // E (dead after scatter_k)
    int*   csr_src  = rank + E;               // E
    float* eap_csr  = (float*)(csr_src + E);  // E*4
    // packed MFMA weight fragments + biases ALIAS the dead `rank` buffer
    // (needs ~397 KB of rank's 1.6 MB; written by pack_k AFTER scatter_k)
    unsigned short* w0hi = (unsigned short*)rank;   // 65536 ushorts
    unsigned short* w0lo = w0hi + 65536;            // 65536
    unsigned short* w1hi = w0lo + 65536;            // 32768
    unsigned short* w1lo = w1hi + 32768;            // 32768
    float* bc0 = (float*)(w1lo + 32768);            // 512 floats
    float* bc1 = bc0 + 512;                         // 512 floats

    dim3 b256(256);
    const int NB = (N + 255) / 256; // 196
    const int NPROJ = (N + 31) / 32; // 1563

    // zero pooled + deg in one memset (adjacent in layout)
    hipMemsetAsync(pooled, 0, (size_t)(G * HID + N) * 4, stream);
    // CSR build (rank-based, no scatter atomics)
    hist_k<<<(E + 255) / 256, b256, 0, stream>>>(dst, deg, rank);
    scan1_k<<<NB, b256, 0, stream>>>(deg, pre, bsum);
    scan2_k<<<1, b256, 0, stream>>>(bsum, NB);
    scatter_k<<<(E + 255) / 256, b256, 0, stream>>>(
        src, dst, edge_attr, W_et, b_et, W_uw, b_uw, W_ua, b_ua,
        pre, bsum, rank, csr_src, eap_csr);
    // weight packing AFTER scatter (rank is dead now; pack output aliases it)
    pack_k<<<52, b256, 0, stream>>>(Wl0, Wr0, bl0, br0, Wl1, Wr1, bl1, br1,
                                    w0hi, w0lo, w1hi, w1lo, bc0, bc1);

    // ---------- layer 0 ----------
    projmm_k<128><<<NPROJ, b256, 0, stream>>>(x, w0hi, w0lo, bc0, xlb, xrb);
    gat_aggr_k<<<GAT_BLOCKS, b256, 0, stream>>>(
        xlb, xrb, eap_csr, We0, att0, pre, bsum, deg, csr_src, bias0, h1);

    // ---------- layer 1 ----------
    projmm_k<64><<<NPROJ, b256, 0, stream>>>(h1, w1hi, w1lo, bc1, xlb, xrb);
    gat_aggr_k<<<GAT_BLOCKS, b256, 0, stream>>>(
        xlb, xrb, eap_csr, We1, att1, pre, bsum, deg, csr_src, bias1, h2);

    // ---------- pooling + head ----------
    pool_k<<<((N + 15) / 16 + 3) / 4, b256, 0, stream>>>(h2, batch, pooled);
    head_k<<<G, dim3(64), 0, stream>>>(
        pooled, batch, W_fc, b_fc, W_res, b_res, W_time, b_time, (float*)d_out);
}